// Round 19
// baseline (131.796 us; speedup 1.0000x reference)
//
#include <hip/hip_runtime.h>

#define LENSZ 11
#define RAD   5
#define TSX   128           // tile width  (8 px per thread in x)
#define TSY   16            // tile height
#define WINX  (TSX + LENSZ - 1)   // 138
#define WINY  (TSY + LENSZ - 1)   // 26
#define NPAIR 69            // source-pair slots per window row
#define PKS   70            // pk plane row stride (uint4 slots)
#define ESS   71            // es plane row stride (u32)
#define IMG_H 1024
#define IMG_W 1024
#define HW    (IMG_H * IMG_W)

// sigmoid(4*(sd-dd)) = 1/(1 + Es(s)/Es(d)), Es = exp2(C4L2*disp)
// C4L2 = -4*log2(e). |disp| <= ~10.4 => Es in [2^-60, 2^60]; bf16 storage
// keeps the range, 0.4% rel err -> ~0.008 output err, threshold 0.02.
#define C4L2  (-5.770780163555854f)
#define DEADC (-3000.0f)    // dead-offset c0: clamp(coc+c0)==0

// NOTE: cvt_pkrtz returns __fp16 ext_vector(2), not _Float16 (R8 lesson).
// NOTE: v_pk_*_f32 inline asm condemned (R6, R11 garbage). v_dot2_f32_f16
// verified OK (R10); v_pk_add_f16+clamp exonerated (R17).
typedef __fp16 v2h __attribute__((ext_vector_type(2)));

// Forced single-instruction packed MAC: acc += a.lo*b.lo + a.hi*b.hi.
__device__ __forceinline__ float dot2acc(float acc, v2h a, v2h b) {
    asm("v_dot2_f32_f16 %0, %1, %2, %0" : "+v"(acc) : "v"(a), "v"(b));
    return acc;
}

// Packed f16 add with VOP3P clamp modifier: per-half clamp to [0,1].
__device__ __forceinline__ v2h pk_add_clamp_f16(v2h a, v2h b) {
    v2h d;
    asm("v_pk_add_f16 %0, %1, %2 clamp" : "=v"(d) : "v"(a), "v"(b));
    return d;
}

// c0 = 0.5 - dist(dy,dx), literal table (R3 lesson: no iterative constexpr
// math on hot paths). Out-of-disk (n>30) -> DEADC so clamp gives exact 0;
// also drives compile-time pruning / half-dead fast path after unrolling.
constexpr float C0V(int dy, int dx) {
    switch (dy * dy + dx * dx) {
        case 0:  return  0.5f;
        case 1:  return -0.5f;
        case 2:  return -0.914213562f;
        case 4:  return -1.5f;
        case 5:  return -1.736067977f;
        case 8:  return -2.328427125f;
        case 9:  return -2.5f;
        case 10: return -2.662277660f;
        case 13: return -3.105551275f;
        case 16: return -3.5f;
        case 17: return -3.623105626f;
        case 18: return -3.742640687f;
        case 20: return -3.972135955f;
        case 25: return -4.5f;
        case 26: return -4.599019514f;
        case 29: return -4.885164807f;
        default: return DEADC;
    }
}

// pk slot XOR swizzle: lane slot-stride is 4 (16B slots) -> naive 8-way bank
// conflict; phys = s ^ ((s>>3)&7) spreads 16 lanes 2-per-bank-group (free).
__device__ __forceinline__ int pswz(int s) { return s ^ ((s >> 3) & 7); }

// Packed per-source-pair data: {coc2(f16x2), r2, g2, b2} + Es as bf16 pair.
__shared__ __align__(16) uint4    pk[WINY * PKS];
__shared__ __align__(16) unsigned es[WINY * ESS];

// One (src-pair, dest) unit. c0a/c0b are compile-time constants after
// unrolling; the DEADC branches fold. rcp shared across the live sides.
__device__ __forceinline__ void unit_op(
    float c0a, float c0b, float Ea, float Eb, float Gj,
    v2h coc2, v2h r2, v2h g2, v2h b2, v2h one2,
    float& nrj, float& ngj, float& nbj, float& dnj)
{
    v2h occ2;
    if (c0b == DEADC) {            // only lo side live: occ_a = 1/fa
        const float fa = fmaf(Ea, Gj, 1.f);
        occ2 = __builtin_amdgcn_cvt_pkrtz(__builtin_amdgcn_rcpf(fa), 0.f);
    } else if (c0a == DEADC) {     // only hi side live: occ_b = 1/fb
        const float fb = fmaf(Eb, Gj, 1.f);
        occ2 = __builtin_amdgcn_cvt_pkrtz(0.f, __builtin_amdgcn_rcpf(fb));
    } else {                       // both live: shared rcp
        const float fa = fmaf(Ea, Gj, 1.f);
        const float fb = fmaf(Eb, Gj, 1.f);
        const float rr = __builtin_amdgcn_rcpf(fa * fb);
        occ2 = __builtin_amdgcn_cvt_pkrtz(rr * fb, rr * fa);
    }
    const v2h c0h = {(__fp16)c0a, (__fp16)c0b};
    const v2h t = pk_add_clamp_f16(coc2, c0h);   // clamp[0,1], 1 inst
    const v2h wh = t * occ2;                     // v_pk_mul_f16
    nrj = dot2acc(nrj, wh, r2);
    ngj = dot2acc(ngj, wh, g2);
    nbj = dot2acc(nbj, wh, b2);
    dnj = dot2acc(dnj, wh, one2);
}

// TWO mirrored window rows (same |dy| -> shared c0 constants) interleaved in
// one kxe loop: both rows' LDS reads issue together, 16 independent rcp
// chains per src-pair -> 2x ILP vs one-row do_row (R19 stall experiment).
template<int ADY, int XMN, int XMX>
__device__ __forceinline__ void do_row2(
    int wy0, int wy1, int tx4, const float (&G)[8], v2h one2,
    float (&nr)[8], float (&ng)[8], float (&nb)[8], float (&dn)[8])
{
#pragma unroll
    for (int kxe = (XMN & ~1); kxe <= XMX + 7; kxe += 2) {
        const int s = tx4 + (kxe >> 1);            // logical pair slot
        const uint4 qA = pk[wy0 * PKS + pswz(s)];
        const uint4 qB = pk[wy1 * PKS + pswz(s)];
        const unsigned ueA = es[wy0 * ESS + s];
        const unsigned ueB = es[wy1 * ESS + s];
        const float EaA = __uint_as_float(ueA << 16);
        const float EbA = __uint_as_float(ueA & 0xffff0000u);
        const float EaB = __uint_as_float(ueB << 16);
        const float EbB = __uint_as_float(ueB & 0xffff0000u);
#pragma unroll
        for (int j = 0; j < 8; ++j) {
            const float c0a = C0V(ADY, kxe - j - RAD);
            const float c0b = C0V(ADY, kxe + 1 - j - RAD);
            if (c0a == DEADC && c0b == DEADC) continue;   // folds post-unroll
            unit_op(c0a, c0b, EaA, EbA, G[j],
                    *reinterpret_cast<const v2h*>(&qA.x),
                    *reinterpret_cast<const v2h*>(&qA.y),
                    *reinterpret_cast<const v2h*>(&qA.z),
                    *reinterpret_cast<const v2h*>(&qA.w), one2,
                    nr[j], ng[j], nb[j], dn[j]);
            unit_op(c0a, c0b, EaB, EbB, G[j],
                    *reinterpret_cast<const v2h*>(&qB.x),
                    *reinterpret_cast<const v2h*>(&qB.y),
                    *reinterpret_cast<const v2h*>(&qB.z),
                    *reinterpret_cast<const v2h*>(&qB.w), one2,
                    nr[j], ng[j], nb[j], dn[j]);
        }
    }
}

// Single center row (dy = 0).
template<int ADY, int XMN, int XMX>
__device__ __forceinline__ void do_row1(
    int wy, int tx4, const float (&G)[8], v2h one2,
    float (&nr)[8], float (&ng)[8], float (&nb)[8], float (&dn)[8])
{
#pragma unroll
    for (int kxe = (XMN & ~1); kxe <= XMX + 7; kxe += 2) {
        const int s = tx4 + (kxe >> 1);
        const uint4 q = pk[wy * PKS + pswz(s)];
        const unsigned ue = es[wy * ESS + s];
        const float Ea = __uint_as_float(ue << 16);
        const float Eb = __uint_as_float(ue & 0xffff0000u);
#pragma unroll
        for (int j = 0; j < 8; ++j) {
            const float c0a = C0V(ADY, kxe - j - RAD);
            const float c0b = C0V(ADY, kxe + 1 - j - RAD);
            if (c0a == DEADC && c0b == DEADC) continue;
            unit_op(c0a, c0b, Ea, Eb, G[j],
                    *reinterpret_cast<const v2h*>(&q.x),
                    *reinterpret_cast<const v2h*>(&q.y),
                    *reinterpret_cast<const v2h*>(&q.z),
                    *reinterpret_cast<const v2h*>(&q.w), one2,
                    nr[j], ng[j], nb[j], dn[j]);
        }
    }
}

__global__ __launch_bounds__(256, 4) void scatter_render_kernel(
    const float* __restrict__ x,      // (B,4,H,W)
    const float* __restrict__ lens,   // (B,1)
    float* __restrict__ out)          // (B,3,H,W)
{
    const int b   = blockIdx.z;
    const int bx0 = blockIdx.x * TSX;
    const int by0 = blockIdx.y * TSY;
    const int tx  = threadIdx.x;      // 0..15
    const int ty  = threadIdx.y;      // 0..15
    const int tid = ty * 16 + tx;

    const float scale = lens[b];
    const float* xb = x + (size_t)b * 4 * HW;

    // ---- stage window: all source-only math done once here (coc, Es);
    // pack {coc2,r2,g2,b2} into a swizzled uint4 slot + Es as bf16-RN pair.
    for (int p = tid; p < WINY * NPAIR; p += 256) {
        int wy = p / NPAIR;
        int sl = p - wy * NPAIR;
        int px = sl * 2;
        int gy = by0 - RAD + wy;  gy = min(max(gy, 0), IMG_H - 1);
        int g0 = bx0 - RAD + px;      g0 = min(max(g0, 0), IMG_W - 1);
        int g1 = bx0 - RAD + px + 1;  g1 = min(max(g1, 0), IMG_W - 1);
        int ba = gy * IMG_W + g0;
        int bb = gy * IMG_W + g1;
        float r0 = xb[ba],          r1 = xb[bb];
        float q0 = xb[ba + HW],     q1 = xb[bb + HW];
        float s0 = xb[ba + 2 * HW], s1 = xb[bb + 2 * HW];
        float d0 = xb[ba + 3 * HW], d1 = xb[bb + 3 * HW];
        uint4 q;
        v2h h;
        h = __builtin_amdgcn_cvt_pkrtz(scale * fabsf(d0), scale * fabsf(d1));
        q.x = *reinterpret_cast<unsigned*>(&h);
        h = __builtin_amdgcn_cvt_pkrtz(r0, r1);
        q.y = *reinterpret_cast<unsigned*>(&h);
        h = __builtin_amdgcn_cvt_pkrtz(q0, q1);
        q.z = *reinterpret_cast<unsigned*>(&h);
        h = __builtin_amdgcn_cvt_pkrtz(s0, s1);
        q.w = *reinterpret_cast<unsigned*>(&h);
        pk[wy * PKS + pswz(sl)] = q;
        // Es pair as round-to-nearest bf16 halves of one u32
        float Ea = __builtin_amdgcn_exp2f(C4L2 * d0);
        float Eb = __builtin_amdgcn_exp2f(C4L2 * d1);
        unsigned ua = (__float_as_uint(Ea) + 0x8000u) >> 16;
        unsigned ub = (__float_as_uint(Eb) + 0x8000u) & 0xffff0000u;
        es[wy * ESS + sl] = ua | ub;
    }
    __syncthreads();

    // per-dest occlusion gate: G_j = 1/Es(dest_j) from the SAME stored bf16
    // value dest reads as source -> self-occlusion exactly 0.5, den >= 0.25.
    const int x8 = 8 * tx;
    float G[8];
#pragma unroll
    for (int j = 0; j < 8; ++j) {
        const int cc = x8 + j + RAD;
        const unsigned ue = es[(ty + RAD) * ESS + (cc >> 1)];
        const float esd = (cc & 1) ? __uint_as_float(ue & 0xffff0000u)
                                   : __uint_as_float(ue << 16);
        G[j] = __builtin_amdgcn_rcpf(esd);
    }
    v2h one2; one2.x = (__fp16)1.f; one2.y = (__fp16)1.f;

    float nr[8] = {0.f, 0.f, 0.f, 0.f, 0.f, 0.f, 0.f, 0.f};
    float ng[8] = {0.f, 0.f, 0.f, 0.f, 0.f, 0.f, 0.f, 0.f};
    float nb[8] = {0.f, 0.f, 0.f, 0.f, 0.f, 0.f, 0.f, 0.f};
    float dn[8] = {0.f, 0.f, 0.f, 0.f, 0.f, 0.f, 0.f, 0.f};

    const int tx4 = 4 * tx;
    // mirrored row pairs interleaved (2x ILP); sched_barrier(0) between
    // groups caps live ranges (R1 spill lesson: never full straight-line).
    do_row2<5, 3, 7>(ty, ty + 10, tx4, G, one2, nr, ng, nb, dn);
    __builtin_amdgcn_sched_barrier(0);
    do_row2<4, 2, 8>(ty + 1, ty + 9, tx4, G, one2, nr, ng, nb, dn);
    __builtin_amdgcn_sched_barrier(0);
    do_row2<3, 1, 9>(ty + 2, ty + 8, tx4, G, one2, nr, ng, nb, dn);
    __builtin_amdgcn_sched_barrier(0);
    do_row2<2, 0, 10>(ty + 3, ty + 7, tx4, G, one2, nr, ng, nb, dn);
    __builtin_amdgcn_sched_barrier(0);
    do_row2<1, 0, 10>(ty + 4, ty + 6, tx4, G, one2, nr, ng, nb, dn);
    __builtin_amdgcn_sched_barrier(0);
    do_row1<0, 0, 10>(ty + 5, tx4, G, one2, nr, ng, nb, dn);

    // epilogue: 8 consecutive pixels -> 2x float4 stores per channel
    const size_t obase = (size_t)b * 3 * HW + (size_t)(by0 + ty) * IMG_W + (bx0 + x8);

    float inv[8];
#pragma unroll
    for (int j = 0; j < 8; ++j)
        inv[j] = __builtin_amdgcn_rcpf(dn[j] + 1e-8f);

#pragma unroll
    for (int h = 0; h < 2; ++h) {
        const int o4 = 4 * h;
        float4 o;
        o.x = nr[o4+0]*inv[o4+0]; o.y = nr[o4+1]*inv[o4+1];
        o.z = nr[o4+2]*inv[o4+2]; o.w = nr[o4+3]*inv[o4+3];
        *reinterpret_cast<float4*>(&out[obase + o4]) = o;
        o.x = ng[o4+0]*inv[o4+0]; o.y = ng[o4+1]*inv[o4+1];
        o.z = ng[o4+2]*inv[o4+2]; o.w = ng[o4+3]*inv[o4+3];
        *reinterpret_cast<float4*>(&out[obase + HW + o4]) = o;
        o.x = nb[o4+0]*inv[o4+0]; o.y = nb[o4+1]*inv[o4+1];
        o.z = nb[o4+2]*inv[o4+2]; o.w = nb[o4+3]*inv[o4+3];
        *reinterpret_cast<float4*>(&out[obase + 2 * HW + o4]) = o;
    }
}

extern "C" void kernel_launch(void* const* d_in, const int* in_sizes, int n_in,
                              void* d_out, int out_size, void* d_ws, size_t ws_size,
                              hipStream_t stream) {
    const float* x    = (const float*)d_in[0];
    const float* lens = (const float*)d_in[1];
    float* out        = (float*)d_out;

    const int B = in_sizes[1];  // lens_effects has B elements

    dim3 block(16, 16, 1);
    dim3 grid(IMG_W / TSX, IMG_H / TSY, B);
    scatter_render_kernel<<<grid, block, 0, stream>>>(x, lens, out);
}

// Round 20
// 96.745 us; speedup vs baseline: 1.3623x; 1.3623x over previous
//
#include <hip/hip_runtime.h>

#define LENSZ 11
#define RAD   5
#define TSX   128           // tile width  (8 px per thread in x)
#define TSY   16            // tile height
#define WINX  (TSX + LENSZ - 1)   // 138
#define WINY  (TSY + LENSZ - 1)   // 26
#define NPAIR 69            // source-pair slots per window row
#define PKS   70            // pk plane row stride (uint4 slots)
#define ESS   71            // es plane row stride (u32)
#define IMG_H 1024
#define IMG_W 1024
#define HW    (IMG_H * IMG_W)

// sigmoid(4*(sd-dd)) = 1/(1 + Es(s)/Es(d)), Es = exp2(C4L2*disp)
// C4L2 = -4*log2(e). |disp| <= ~10.4 => Es in [2^-60, 2^60]; bf16 storage
// keeps the range, 0.4% rel err -> ~0.008 output err, threshold 0.02.
#define C4L2  (-5.770780163555854f)
#define DEADC (-3000.0f)    // dead-offset c0: clamp(coc+c0)==0

// NOTE: cvt_pkrtz returns __fp16 ext_vector(2), not _Float16 (R8 lesson).
// NOTE: v_pk_*_f32 inline asm condemned (R6, R11 garbage). v_dot2_f32_f16
// verified OK (R10). R19 lesson: sched_barrier fences + manual ILP
// interleave regress badly; compiler's natural schedule is near-optimal.
typedef __fp16 v2h __attribute__((ext_vector_type(2)));

// Forced single-instruction packed MAC: acc += a.lo*b.lo + a.hi*b.hi.
__device__ __forceinline__ float dot2acc(float acc, v2h a, v2h b) {
    asm("v_dot2_f32_f16 %0, %1, %2, %0" : "+v"(acc) : "v"(a), "v"(b));
    return acc;
}

// c0 = 0.5 - dist(dy,dx), literal table (R3 lesson: no iterative constexpr
// math on hot paths). Out-of-disk (n>30) -> DEADC so clamp gives exact 0;
// also drives compile-time pruning / half-dead fast path after unrolling.
constexpr float C0V(int dy, int dx) {
    switch (dy * dy + dx * dx) {
        case 0:  return  0.5f;
        case 1:  return -0.5f;
        case 2:  return -0.914213562f;
        case 4:  return -1.5f;
        case 5:  return -1.736067977f;
        case 8:  return -2.328427125f;
        case 9:  return -2.5f;
        case 10: return -2.662277660f;
        case 13: return -3.105551275f;
        case 16: return -3.5f;
        case 17: return -3.623105626f;
        case 18: return -3.742640687f;
        case 20: return -3.972135955f;
        case 25: return -4.5f;
        case 26: return -4.599019514f;
        case 29: return -4.885164807f;
        default: return DEADC;
    }
}

// pk slot XOR swizzle: lane slot-stride is 4 (16B slots) -> naive 8-way bank
// conflict; phys = s ^ ((s>>3)&7) spreads 16 lanes 2-per-bank-group (free).
__device__ __forceinline__ int pswz(int s) { return s ^ ((s >> 3) & 7); }

// Packed per-source-pair data: {coc2(f16x2), r2, g2, b2} + Es as bf16 pair.
__shared__ __align__(16) uint4    pk[WINY * PKS];
__shared__ __align__(16) unsigned es[WINY * ESS];

// One window row at runtime y-index `wy`, compile-time |dy| and disk bounds.
// Per src-pair: 1x ds_read_b128 + 1x ds_read_b32, 2 VALU unpack. rcp shared
// across the src pair; w0/w packed f16; accumulate via forced v_dot2_f32_f16.
// Half-dead units (one side out-of-disk) take a cheaper scalar-occ path.
template<int ADY, int XMN, int XMX>
__device__ __forceinline__ void do_row(
    int wy, int tx4, const float (&G)[8], v2h one2,
    float (&nr)[8], float (&ng)[8], float (&nb)[8], float (&dn)[8])
{
    const v2h zero2 = {(__fp16)0.f, (__fp16)0.f};
    const v2h onee2 = {(__fp16)1.f, (__fp16)1.f};
#pragma unroll
    for (int kxe = (XMN & ~1); kxe <= XMX + 7; kxe += 2) {
        const int s = tx4 + (kxe >> 1);            // logical pair slot
        const uint4 q = pk[wy * PKS + pswz(s)];
        const v2h coc2 = *reinterpret_cast<const v2h*>(&q.x);
        const v2h r2   = *reinterpret_cast<const v2h*>(&q.y);
        const v2h g2   = *reinterpret_cast<const v2h*>(&q.z);
        const v2h b2   = *reinterpret_cast<const v2h*>(&q.w);
        const unsigned ue = es[wy * ESS + s];
        const float Ea = __uint_as_float(ue << 16);
        const float Eb = __uint_as_float(ue & 0xffff0000u);
#pragma unroll
        for (int j = 0; j < 8; ++j) {
            const float c0a = C0V(ADY, kxe - j - RAD);
            const float c0b = C0V(ADY, kxe + 1 - j - RAD);
            if (c0a == DEADC && c0b == DEADC) continue;   // folds post-unroll
            v2h occ2;
            if (c0b == DEADC) {            // only lo side live: occ_a = 1/fa
                const float fa = fmaf(Ea, G[j], 1.f);
                occ2 = __builtin_amdgcn_cvt_pkrtz(__builtin_amdgcn_rcpf(fa), 0.f);
            } else if (c0a == DEADC) {     // only hi side live: occ_b = 1/fb
                const float fb = fmaf(Eb, G[j], 1.f);
                occ2 = __builtin_amdgcn_cvt_pkrtz(0.f, __builtin_amdgcn_rcpf(fb));
            } else {                       // both live: shared rcp
                const float fa = fmaf(Ea, G[j], 1.f);
                const float fb = fmaf(Eb, G[j], 1.f);
                const float rr = __builtin_amdgcn_rcpf(fa * fb);
                occ2 = __builtin_amdgcn_cvt_pkrtz(rr * fb, rr * fa);
            }
            const v2h c0h = {(__fp16)c0a, (__fp16)c0b};
            v2h t = coc2 + c0h;                          // v_pk_add_f16
            t = __builtin_elementwise_max(t, zero2);     // v_pk_max_f16
            t = __builtin_elementwise_min(t, onee2);     // v_pk_min_f16
            const v2h wh = t * occ2;                     // v_pk_mul_f16
            nr[j] = dot2acc(nr[j], wh, r2);
            ng[j] = dot2acc(ng[j], wh, g2);
            nb[j] = dot2acc(nb[j], wh, b2);
            dn[j] = dot2acc(dn[j], wh, one2);
        }
    }
}

__global__ __launch_bounds__(256, 4) void scatter_render_kernel(
    const float* __restrict__ x,      // (B,4,H,W)
    const float* __restrict__ lens,   // (B,1)
    float* __restrict__ out)          // (B,3,H,W)
{
    const int b   = blockIdx.z;
    const int bx0 = blockIdx.x * TSX;
    const int by0 = blockIdx.y * TSY;
    const int tx  = threadIdx.x;      // 0..15
    const int ty  = threadIdx.y;      // 0..15
    const int tid = ty * 16 + tx;

    const float scale = lens[b];
    const float* xb = x + (size_t)b * 4 * HW;

    // ---- stage window: all source-only math done once here (coc, Es);
    // pack {coc2,r2,g2,b2} into a swizzled uint4 slot + Es as bf16-RN pair.
    for (int p = tid; p < WINY * NPAIR; p += 256) {
        int wy = p / NPAIR;
        int sl = p - wy * NPAIR;
        int px = sl * 2;
        int gy = by0 - RAD + wy;  gy = min(max(gy, 0), IMG_H - 1);
        int g0 = bx0 - RAD + px;      g0 = min(max(g0, 0), IMG_W - 1);
        int g1 = bx0 - RAD + px + 1;  g1 = min(max(g1, 0), IMG_W - 1);
        int ba = gy * IMG_W + g0;
        int bb = gy * IMG_W + g1;
        float r0 = xb[ba],          r1 = xb[bb];
        float q0 = xb[ba + HW],     q1 = xb[bb + HW];
        float s0 = xb[ba + 2 * HW], s1 = xb[bb + 2 * HW];
        float d0 = xb[ba + 3 * HW], d1 = xb[bb + 3 * HW];
        uint4 q;
        v2h h;
        h = __builtin_amdgcn_cvt_pkrtz(scale * fabsf(d0), scale * fabsf(d1));
        q.x = *reinterpret_cast<unsigned*>(&h);
        h = __builtin_amdgcn_cvt_pkrtz(r0, r1);
        q.y = *reinterpret_cast<unsigned*>(&h);
        h = __builtin_amdgcn_cvt_pkrtz(q0, q1);
        q.z = *reinterpret_cast<unsigned*>(&h);
        h = __builtin_amdgcn_cvt_pkrtz(s0, s1);
        q.w = *reinterpret_cast<unsigned*>(&h);
        pk[wy * PKS + pswz(sl)] = q;
        // Es pair as round-to-nearest bf16 halves of one u32
        float Ea = __builtin_amdgcn_exp2f(C4L2 * d0);
        float Eb = __builtin_amdgcn_exp2f(C4L2 * d1);
        unsigned ua = (__float_as_uint(Ea) + 0x8000u) >> 16;
        unsigned ub = (__float_as_uint(Eb) + 0x8000u) & 0xffff0000u;
        es[wy * ESS + sl] = ua | ub;
    }
    __syncthreads();

    // per-dest occlusion gate: G_j = 1/Es(dest_j) from the SAME stored bf16
    // value dest reads as source -> self-occlusion exactly 0.5, den >= 0.25.
    const int x8 = 8 * tx;
    float G[8];
#pragma unroll
    for (int j = 0; j < 8; ++j) {
        const int cc = x8 + j + RAD;
        const unsigned ue = es[(ty + RAD) * ESS + (cc >> 1)];
        const float esd = (cc & 1) ? __uint_as_float(ue & 0xffff0000u)
                                   : __uint_as_float(ue << 16);
        G[j] = __builtin_amdgcn_rcpf(esd);
    }
    v2h one2; one2.x = (__fp16)1.f; one2.y = (__fp16)1.f;

    float nr[8] = {0.f, 0.f, 0.f, 0.f, 0.f, 0.f, 0.f, 0.f};
    float ng[8] = {0.f, 0.f, 0.f, 0.f, 0.f, 0.f, 0.f, 0.f};
    float nb[8] = {0.f, 0.f, 0.f, 0.f, 0.f, 0.f, 0.f, 0.f};
    float dn[8] = {0.f, 0.f, 0.f, 0.f, 0.f, 0.f, 0.f, 0.f};

    const int tx4 = 4 * tx;
    // mirrored row pairs share |dy| -> c0 compile-time; runtime 2-trip loops
    // keep live ranges bounded (R1's full unroll spilled).
#pragma unroll 1
    for (int t = 0; t < 2; ++t)
        do_row<5, 3, 7>(ty + t * 10, tx4, G, one2, nr, ng, nb, dn);
#pragma unroll 1
    for (int t = 0; t < 2; ++t)
        do_row<4, 2, 8>(ty + 1 + t * 8, tx4, G, one2, nr, ng, nb, dn);
#pragma unroll 1
    for (int t = 0; t < 2; ++t)
        do_row<3, 1, 9>(ty + 2 + t * 6, tx4, G, one2, nr, ng, nb, dn);
#pragma unroll 1
    for (int t = 0; t < 2; ++t)
        do_row<2, 0, 10>(ty + 3 + t * 4, tx4, G, one2, nr, ng, nb, dn);
#pragma unroll 1
    for (int t = 0; t < 2; ++t)
        do_row<1, 0, 10>(ty + 4 + t * 2, tx4, G, one2, nr, ng, nb, dn);
    do_row<0, 0, 10>(ty + 5, tx4, G, one2, nr, ng, nb, dn);

    // epilogue: 8 consecutive pixels -> 2x float4 stores per channel
    const size_t obase = (size_t)b * 3 * HW + (size_t)(by0 + ty) * IMG_W + (bx0 + x8);

    float inv[8];
#pragma unroll
    for (int j = 0; j < 8; ++j)
        inv[j] = __builtin_amdgcn_rcpf(dn[j] + 1e-8f);

#pragma unroll
    for (int h = 0; h < 2; ++h) {
        const int o4 = 4 * h;
        float4 o;
        o.x = nr[o4+0]*inv[o4+0]; o.y = nr[o4+1]*inv[o4+1];
        o.z = nr[o4+2]*inv[o4+2]; o.w = nr[o4+3]*inv[o4+3];
        *reinterpret_cast<float4*>(&out[obase + o4]) = o;
        o.x = ng[o4+0]*inv[o4+0]; o.y = ng[o4+1]*inv[o4+1];
        o.z = ng[o4+2]*inv[o4+2]; o.w = ng[o4+3]*inv[o4+3];
        *reinterpret_cast<float4*>(&out[obase + HW + o4]) = o;
        o.x = nb[o4+0]*inv[o4+0]; o.y = nb[o4+1]*inv[o4+1];
        o.z = nb[o4+2]*inv[o4+2]; o.w = nb[o4+3]*inv[o4+3];
        *reinterpret_cast<float4*>(&out[obase + 2 * HW + o4]) = o;
    }
}

extern "C" void kernel_launch(void* const* d_in, const int* in_sizes, int n_in,
                              void* d_out, int out_size, void* d_ws, size_t ws_size,
                              hipStream_t stream) {
    const float* x    = (const float*)d_in[0];
    const float* lens = (const float*)d_in[1];
    float* out        = (float*)d_out;

    const int B = in_sizes[1];  // lens_effects has B elements

    dim3 block(16, 16, 1);
    dim3 grid(IMG_W / TSX, IMG_H / TSY, B);
    scatter_render_kernel<<<grid, block, 0, stream>>>(x, lens, out);
}